// Round 1
// baseline (1956.674 us; speedup 1.0000x reference)
//
#include <hip/hip_runtime.h>

#define B_ 4
#define T_ 2048
#define C_ 1024
#define H_ 16
#define D_ 64

// ---------------------------------------------------------------------------
// QKV projection: X[8192,1024] @ W[1024,3072] + bias.
// Epilogue splits q/k/v, transposes to [B,H,T,D], folds D^-0.5 into q.
// 64x64 tile, BK=16, 256 threads, 4x4 micro-tile per thread, fp32.
// ---------------------------------------------------------------------------
__global__ __launch_bounds__(256) void qkv_gemm(
    const float* __restrict__ X, const float* __restrict__ W,
    const float* __restrict__ bias,
    float* __restrict__ qb, float* __restrict__ kb, float* __restrict__ vb)
{
    __shared__ float As[16][68];   // [k][m], padded
    __shared__ float Bs[16][64];   // [k][n]
    const int tid = threadIdx.x;
    const int tx = tid & 15, ty = tid >> 4;
    const int m0 = blockIdx.y * 64;
    const int n0 = blockIdx.x * 64;

    float acc[4][4] = {};

    for (int k0 = 0; k0 < 1024; k0 += 16) {
        const int idx = tid * 4;
        {
            int m = idx >> 4, k = idx & 15;
            float4 a = *(const float4*)(X + (size_t)(m0 + m) * 1024 + (k0 + k));
            As[k+0][m] = a.x; As[k+1][m] = a.y; As[k+2][m] = a.z; As[k+3][m] = a.w;
        }
        {
            int k = idx >> 6, n = idx & 63;
            *(float4*)&Bs[k][n] = *(const float4*)(W + (size_t)(k0 + k) * 3072 + (n0 + n));
        }
        __syncthreads();
        #pragma unroll
        for (int kk = 0; kk < 16; ++kk) {
            float4 a4 = *(const float4*)&As[kk][ty*4];
            float4 b4 = *(const float4*)&Bs[kk][tx*4];
            float av[4] = {a4.x, a4.y, a4.z, a4.w};
            float bv[4] = {b4.x, b4.y, b4.z, b4.w};
            #pragma unroll
            for (int r = 0; r < 4; ++r)
                #pragma unroll
                for (int c = 0; c < 4; ++c)
                    acc[r][c] += av[r] * bv[c];
        }
        __syncthreads();
    }

    // tile is entirely within one (sel, head) since 64 | 1024
    const int sel = n0 >> 10;
    const int h = (n0 & 1023) >> 6;
    float* dst = (sel == 0) ? qb : ((sel == 1) ? kb : vb);
    const float scale = (sel == 0) ? 0.125f : 1.0f;   // D^-0.5 folded into q
    float4 bb = *(const float4*)(bias + n0 + tx*4);
    #pragma unroll
    for (int r = 0; r < 4; ++r) {
        int m = m0 + ty*4 + r;
        int b = m >> 11;          // / 2048
        int t = m & 2047;
        float4 o;
        o.x = (acc[r][0] + bb.x) * scale;
        o.y = (acc[r][1] + bb.y) * scale;
        o.z = (acc[r][2] + bb.z) * scale;
        o.w = (acc[r][3] + bb.w) * scale;
        *(float4*)(dst + ((size_t)((b*16 + h)*2048 + t)) * 64 + tx*4) = o;
    }
}

// ---------------------------------------------------------------------------
// Flash-style causal attention. One block = 64 query rows of one (b,h).
// Online softmax (m,l per row), K/V/P tiles staged in LDS, O in registers.
// Output written directly in [B,T,C] layout for the proj GEMM.
// ---------------------------------------------------------------------------
__global__ __launch_bounds__(256) void attn_kernel(
    const float* __restrict__ qb, const float* __restrict__ kb,
    const float* __restrict__ vb, float* __restrict__ ab)
{
    const int q0 = blockIdx.x * 64;
    const int bh = blockIdx.y;            // b*16 + h
    const int b = bh >> 4, h = bh & 15;
    const float* Q = qb + (size_t)bh * T_ * 64;
    const float* K = kb + (size_t)bh * T_ * 64;
    const float* V = vb + (size_t)bh * 64 * T_;

    __shared__ float Qs[64][68];   // [d][qrow]  (transposed)
    __shared__ float Ks[64][68];   // [d][krow]  (transposed)
    __shared__ float Vs[64][68];   // [krow][d]
    __shared__ float Ps[64][68];   // [qrow][k]
    __shared__ float red[64][17];
    __shared__ float m_s[64], l_s[64], alpha_s[64];

    const int tid = threadIdx.x;
    const int tx = tid & 15, ty = tid >> 4;

    // load Q tile (transposed into LDS)
    #pragma unroll
    for (int i = 0; i < 4; ++i) {
        int f = tid + 256*i;
        int row = f >> 4;
        int d4 = (f & 15) * 4;
        float4 v = *(const float4*)(Q + (size_t)(q0 + row) * 64 + d4);
        Qs[d4+0][row] = v.x; Qs[d4+1][row] = v.y; Qs[d4+2][row] = v.z; Qs[d4+3][row] = v.w;
    }
    if (tid < 64) { m_s[tid] = -1e30f; l_s[tid] = 0.0f; }
    float acc[4][4] = {};
    __syncthreads();

    for (int j0 = 0; j0 <= q0; j0 += 64) {
        // stage K (transposed) and V tiles
        #pragma unroll
        for (int i = 0; i < 4; ++i) {
            int f = tid + 256*i;
            int row = f >> 4;
            int d4 = (f & 15) * 4;
            float4 kv = *(const float4*)(K + (size_t)(j0 + row) * 64 + d4);
            Ks[d4+0][row] = kv.x; Ks[d4+1][row] = kv.y; Ks[d4+2][row] = kv.z; Ks[d4+3][row] = kv.w;
            *(float4*)&Vs[row][d4] = *(const float4*)(V + (size_t)(j0 + row) * 64 + d4);
        }
        __syncthreads();

        // S = Q @ K^T  (q pre-scaled by D^-0.5)
        float s[4][4] = {};
        #pragma unroll 8
        for (int d = 0; d < 64; ++d) {
            float4 q4 = *(const float4*)&Qs[d][ty*4];
            float4 k4 = *(const float4*)&Ks[d][tx*4];
            float qa[4] = {q4.x, q4.y, q4.z, q4.w};
            float ka[4] = {k4.x, k4.y, k4.z, k4.w};
            #pragma unroll
            for (int r = 0; r < 4; ++r)
                #pragma unroll
                for (int c = 0; c < 4; ++c)
                    s[r][c] += qa[r] * ka[c];
        }

        // causal mask — only the diagonal tile is partially masked
        if (j0 == q0) {
            #pragma unroll
            for (int r = 0; r < 4; ++r)
                #pragma unroll
                for (int c = 0; c < 4; ++c)
                    if (tx*4 + c > ty*4 + r) s[r][c] = -1e30f;
        }

        // row-max partials
        #pragma unroll
        for (int r = 0; r < 4; ++r)
            red[ty*4+r][tx] = fmaxf(fmaxf(s[r][0], s[r][1]), fmaxf(s[r][2], s[r][3]));
        __syncthreads();
        if (tid < 64) {
            float m = red[tid][0];
            #pragma unroll
            for (int i = 1; i < 16; ++i) m = fmaxf(m, red[tid][i]);
            float m_old = m_s[tid];
            float m_new = fmaxf(m_old, m);
            float a = __expf(m_old - m_new);   // 0 on first tile
            m_s[tid] = m_new;
            alpha_s[tid] = a;
            l_s[tid] *= a;
        }
        __syncthreads();

        // P = exp(S - m_new); row-sum partials
        #pragma unroll
        for (int r = 0; r < 4; ++r) {
            float mn = m_s[ty*4+r];
            float ps = 0.0f;
            #pragma unroll
            for (int c = 0; c < 4; ++c) {
                float p = __expf(s[r][c] - mn);
                Ps[ty*4+r][tx*4+c] = p;
                ps += p;
            }
            red[ty*4+r][tx] = ps;
        }
        __syncthreads();
        if (tid < 64) {
            float sum = 0.0f;
            #pragma unroll
            for (int i = 0; i < 16; ++i) sum += red[tid][i];
            l_s[tid] += sum;
        }

        // O = O*alpha + P @ V
        float al[4];
        #pragma unroll
        for (int r = 0; r < 4; ++r) al[r] = alpha_s[ty*4+r];
        #pragma unroll
        for (int r = 0; r < 4; ++r)
            #pragma unroll
            for (int c = 0; c < 4; ++c)
                acc[r][c] *= al[r];

        #pragma unroll 4
        for (int kb4 = 0; kb4 < 16; ++kb4) {
            float pr[4][4];
            #pragma unroll
            for (int r = 0; r < 4; ++r) {
                float4 p4 = *(const float4*)&Ps[ty*4+r][kb4*4];
                pr[r][0]=p4.x; pr[r][1]=p4.y; pr[r][2]=p4.z; pr[r][3]=p4.w;
            }
            #pragma unroll
            for (int i = 0; i < 4; ++i) {
                float4 v4 = *(const float4*)&Vs[kb4*4+i][tx*4];
                float vv[4] = {v4.x, v4.y, v4.z, v4.w};
                #pragma unroll
                for (int r = 0; r < 4; ++r)
                    #pragma unroll
                    for (int c = 0; c < 4; ++c)
                        acc[r][c] += pr[r][i] * vv[c];
            }
        }
        __syncthreads();   // protects Ks/Vs/Ps/red reuse next iter; l_s final
    }

    // finalize and write [B,T,C]
    #pragma unroll
    for (int r = 0; r < 4; ++r) {
        float linv = 1.0f / l_s[ty*4+r];
        float4 o;
        o.x = acc[r][0] * linv;
        o.y = acc[r][1] * linv;
        o.z = acc[r][2] * linv;
        o.w = acc[r][3] * linv;
        *(float4*)(ab + ((size_t)(b*2048 + q0 + ty*4 + r)) * 1024 + h*64 + tx*4) = o;
    }
}

// ---------------------------------------------------------------------------
// Output projection: A[8192,1024] @ W[1024,1024] + bias -> out
// ---------------------------------------------------------------------------
__global__ __launch_bounds__(256) void proj_gemm(
    const float* __restrict__ A, const float* __restrict__ W,
    const float* __restrict__ bias, float* __restrict__ out)
{
    __shared__ float As[16][68];
    __shared__ float Bs[16][64];
    const int tid = threadIdx.x;
    const int tx = tid & 15, ty = tid >> 4;
    const int m0 = blockIdx.y * 64;
    const int n0 = blockIdx.x * 64;

    float acc[4][4] = {};

    for (int k0 = 0; k0 < 1024; k0 += 16) {
        const int idx = tid * 4;
        {
            int m = idx >> 4, k = idx & 15;
            float4 a = *(const float4*)(A + (size_t)(m0 + m) * 1024 + (k0 + k));
            As[k+0][m] = a.x; As[k+1][m] = a.y; As[k+2][m] = a.z; As[k+3][m] = a.w;
        }
        {
            int k = idx >> 6, n = idx & 63;
            *(float4*)&Bs[k][n] = *(const float4*)(W + (size_t)(k0 + k) * 1024 + (n0 + n));
        }
        __syncthreads();
        #pragma unroll
        for (int kk = 0; kk < 16; ++kk) {
            float4 a4 = *(const float4*)&As[kk][ty*4];
            float4 b4 = *(const float4*)&Bs[kk][tx*4];
            float av[4] = {a4.x, a4.y, a4.z, a4.w};
            float bv[4] = {b4.x, b4.y, b4.z, b4.w};
            #pragma unroll
            for (int r = 0; r < 4; ++r)
                #pragma unroll
                for (int c = 0; c < 4; ++c)
                    acc[r][c] += av[r] * bv[c];
        }
        __syncthreads();
    }

    float4 bb = *(const float4*)(bias + n0 + tx*4);
    #pragma unroll
    for (int r = 0; r < 4; ++r) {
        int m = m0 + ty*4 + r;
        float4 o;
        o.x = acc[r][0] + bb.x;
        o.y = acc[r][1] + bb.y;
        o.z = acc[r][2] + bb.z;
        o.w = acc[r][3] + bb.w;
        *(float4*)(out + (size_t)m * 1024 + n0 + tx*4) = o;
    }
}

extern "C" void kernel_launch(void* const* d_in, const int* in_sizes, int n_in,
                              void* d_out, int out_size, void* d_ws, size_t ws_size,
                              hipStream_t stream) {
    const float* x      = (const float*)d_in[0];   // [B,T,C]
    const float* w_qkv  = (const float*)d_in[1];   // [C,3C]
    const float* b_qkv  = (const float*)d_in[2];   // [3C]
    const float* w_proj = (const float*)d_in[3];   // [C,C]
    const float* b_proj = (const float*)d_in[4];   // [C]
    float* out = (float*)d_out;                    // [B,T,C]

    const size_t NE = (size_t)B_ * H_ * T_ * D_;   // 8388608 elements
    float* qb = (float*)d_ws;                      // [B,H,T,D]
    float* kb = qb + NE;
    float* vb = kb + NE;
    float* ab = vb + NE;                           // [B,T,C]
    // total workspace: 4 * 32 MiB = 128 MiB fp32

    qkv_gemm<<<dim3(48, 128), 256, 0, stream>>>(x, w_qkv, b_qkv, qb, kb, vb);
    attn_kernel<<<dim3(32, 64), 256, 0, stream>>>(qb, kb, vb, ab);
    proj_gemm<<<dim3(16, 128), 256, 0, stream>>>(ab, w_proj, b_proj, out);
}

// Round 2
// 423.904 us; speedup vs baseline: 4.6158x; 4.6158x over previous
//
#include <hip/hip_runtime.h>

#define B_ 4
#define T_ 2048
#define C_ 1024
#define H_ 16
#define D_ 64

typedef __attribute__((ext_vector_type(8))) short short8;
typedef __attribute__((ext_vector_type(4))) float f32x4;

// float -> bf16 with round-to-nearest-even
__device__ inline unsigned short f2bf(float f) {
    union { float f; unsigned u; } v; v.f = f;
    unsigned r = v.u + 0x7fffu + ((v.u >> 16) & 1u);
    return (unsigned short)(r >> 16);
}

// async 16B global -> LDS (wave-uniform LDS base + lane*16)
__device__ inline void async_ld16(const void* g, void* lds) {
    __builtin_amdgcn_global_load_lds(
        (const __attribute__((address_space(1))) unsigned int*)g,
        (__attribute__((address_space(3))) unsigned int*)lds, 16, 0, 0);
}

// ---------------------------------------------------------------------------
// fp32 -> bf16 flat convert (n multiple of 4)
// ---------------------------------------------------------------------------
__global__ __launch_bounds__(256) void convert_bf16(
    const float* __restrict__ src, unsigned short* __restrict__ dst, int n)
{
    int i = (blockIdx.x * 256 + threadIdx.x) * 4;
    if (i >= n) return;
    float4 v = *(const float4*)(src + i);
    ushort4 o;
    o.x = f2bf(v.x); o.y = f2bf(v.y); o.z = f2bf(v.z); o.w = f2bf(v.w);
    *(ushort4*)(dst + i) = o;
}

// ---------------------------------------------------------------------------
// src[R][C] fp32 -> dst[C][R] bf16 (32x32 LDS tiles, coalesced both sides)
// ---------------------------------------------------------------------------
__global__ __launch_bounds__(256) void transpose_convert(
    const float* __restrict__ src, unsigned short* __restrict__ dst, int R, int C)
{
    __shared__ float tile[32][33];
    const int bx = blockIdx.x;   // over C/32
    const int by = blockIdx.y;   // over R/32
    const int tx = threadIdx.x & 31, ty = threadIdx.x >> 5;
    #pragma unroll
    for (int r = 0; r < 32; r += 8)
        tile[ty + r][tx] = src[(size_t)(by*32 + ty + r) * C + bx*32 + tx];
    __syncthreads();
    #pragma unroll
    for (int r = 0; r < 32; r += 8)
        dst[(size_t)(bx*32 + ty + r) * R + by*32 + tx] = f2bf(tile[tx][ty + r]);
}

// ---------------------------------------------------------------------------
// bf16 MFMA GEMM, m97 structure: 128x128 tile, BK=32, global_load_lds(16B),
// A[m][k] bf16, BT[n][k] bf16, 4 waves (2x2), each 64x64 via 4x4 MFMA frags.
// QKV epilogue: +bias, split q/k/v, q*0.125, q/k -> [B,H,T,D], v -> [B,H,D,T].
// ---------------------------------------------------------------------------
__global__ __launch_bounds__(256) void gemm_qkv(
    const unsigned short* __restrict__ A,   // [8192][1024] bf16
    const unsigned short* __restrict__ BT,  // [3072][1024] bf16
    const float* __restrict__ bias,         // [3072] fp32
    unsigned short* __restrict__ qb, unsigned short* __restrict__ kb,
    unsigned short* __restrict__ vtb)
{
    __shared__ unsigned short As[128 * 32];
    __shared__ unsigned short Bs[128 * 32];
    const int tid = threadIdx.x;
    const int wave = tid >> 6, lane = tid & 63;
    const int wm = wave >> 1, wn = wave & 1;
    const int l15 = lane & 15, lq = lane >> 4;
    const int m0 = blockIdx.y * 128, n0 = blockIdx.x * 128;
    const int srow = tid >> 2;      // staging row 0..63
    const int sg = tid & 3;         // 16B group within 64B row

    f32x4 acc[4][4] = {};

    for (int k0 = 0; k0 < 1024; k0 += 32) {
        async_ld16(A  + (size_t)(m0 + srow)      * 1024 + k0 + sg*8, (char*)As + wave*1024);
        async_ld16(A  + (size_t)(m0 + 64 + srow) * 1024 + k0 + sg*8, (char*)As + 4096 + wave*1024);
        async_ld16(BT + (size_t)(n0 + srow)      * 1024 + k0 + sg*8, (char*)Bs + wave*1024);
        async_ld16(BT + (size_t)(n0 + 64 + srow) * 1024 + k0 + sg*8, (char*)Bs + 4096 + wave*1024);
        __syncthreads();
        short8 af[4], bf[4];
        #pragma unroll
        for (int i = 0; i < 4; ++i) {
            af[i] = *(const short8*)&As[(wm*64 + i*16 + l15) * 32 + lq*8];
            bf[i] = *(const short8*)&Bs[(wn*64 + i*16 + l15) * 32 + lq*8];
        }
        #pragma unroll
        for (int mi = 0; mi < 4; ++mi)
            #pragma unroll
            for (int ni = 0; ni < 4; ++ni)
                acc[mi][ni] = __builtin_amdgcn_mfma_f32_16x16x32_bf16(
                    af[mi], bf[ni], acc[mi][ni], 0, 0, 0);
        __syncthreads();
    }

    const int sel = n0 >> 10;   // 0=q 1=k 2=v (128 | 1024 so constant per block)
    #pragma unroll
    for (int mi = 0; mi < 4; ++mi) {
        #pragma unroll
        for (int ni = 0; ni < 4; ++ni) {
            const int n = n0 + wn*64 + ni*16 + l15;
            const float bs = bias[n];
            const int h = (n >> 6) & 15, d = n & 63;
            #pragma unroll
            for (int r = 0; r < 4; ++r) {
                const int m = m0 + wm*64 + mi*16 + lq*4 + r;  // C-layout row
                const int b = m >> 11, t = m & 2047;
                const size_t bh = (size_t)(b*16 + h);
                float v = acc[mi][ni][r] + bs;
                if (sel == 0)      qb[(bh*2048 + t)*64 + d] = f2bf(v * 0.125f);
                else if (sel == 1) kb[(bh*2048 + t)*64 + d] = f2bf(v);
                else               vtb[(bh*64 + d)*2048 + t] = f2bf(v);
            }
        }
    }
}

// ---------------------------------------------------------------------------
// Output projection GEMM: ab[8192][1024] bf16 @ wprojT[1024][1024] bf16 + bias
// -> out fp32 [8192][1024]
// ---------------------------------------------------------------------------
__global__ __launch_bounds__(256) void gemm_proj(
    const unsigned short* __restrict__ A,   // [8192][1024] bf16
    const unsigned short* __restrict__ BT,  // [1024][1024] bf16
    const float* __restrict__ bias,         // [1024]
    float* __restrict__ out)
{
    __shared__ unsigned short As[128 * 32];
    __shared__ unsigned short Bs[128 * 32];
    const int tid = threadIdx.x;
    const int wave = tid >> 6, lane = tid & 63;
    const int wm = wave >> 1, wn = wave & 1;
    const int l15 = lane & 15, lq = lane >> 4;
    const int m0 = blockIdx.y * 128, n0 = blockIdx.x * 128;
    const int srow = tid >> 2, sg = tid & 3;

    f32x4 acc[4][4] = {};

    for (int k0 = 0; k0 < 1024; k0 += 32) {
        async_ld16(A  + (size_t)(m0 + srow)      * 1024 + k0 + sg*8, (char*)As + wave*1024);
        async_ld16(A  + (size_t)(m0 + 64 + srow) * 1024 + k0 + sg*8, (char*)As + 4096 + wave*1024);
        async_ld16(BT + (size_t)(n0 + srow)      * 1024 + k0 + sg*8, (char*)Bs + wave*1024);
        async_ld16(BT + (size_t)(n0 + 64 + srow) * 1024 + k0 + sg*8, (char*)Bs + 4096 + wave*1024);
        __syncthreads();
        short8 af[4], bf[4];
        #pragma unroll
        for (int i = 0; i < 4; ++i) {
            af[i] = *(const short8*)&As[(wm*64 + i*16 + l15) * 32 + lq*8];
            bf[i] = *(const short8*)&Bs[(wn*64 + i*16 + l15) * 32 + lq*8];
        }
        #pragma unroll
        for (int mi = 0; mi < 4; ++mi)
            #pragma unroll
            for (int ni = 0; ni < 4; ++ni)
                acc[mi][ni] = __builtin_amdgcn_mfma_f32_16x16x32_bf16(
                    af[mi], bf[ni], acc[mi][ni], 0, 0, 0);
        __syncthreads();
    }

    #pragma unroll
    for (int mi = 0; mi < 4; ++mi)
        #pragma unroll
        for (int ni = 0; ni < 4; ++ni) {
            const int n = n0 + wn*64 + ni*16 + l15;
            const float bs = bias[n];
            #pragma unroll
            for (int r = 0; r < 4; ++r) {
                const int m = m0 + wm*64 + mi*16 + lq*4 + r;
                out[(size_t)m * 1024 + n] = acc[mi][ni][r] + bs;
            }
        }
}

// ---------------------------------------------------------------------------
// MFMA flash attention, causal. Block = 64 q-rows of one (b,h), 4 waves x 16
// rows. QK^T and PV via mfma_f32_16x16x32_bf16; online softmax in registers
// (C-layout rows, shfl_xor over the 16 lanes holding the row's columns);
// P transits C-layout -> A-layout through a wave-private LDS tile.
// q pre-scaled by D^-0.5 in gemm_qkv. Writes ab bf16 [B*T][C].
// ---------------------------------------------------------------------------
__global__ __launch_bounds__(256) void attn_mfma(
    const unsigned short* __restrict__ qb,   // [B,H,T,D]
    const unsigned short* __restrict__ kb,   // [B,H,T,D]
    const unsigned short* __restrict__ vtb,  // [B,H,D,T]
    unsigned short* __restrict__ ab)         // [B*T][C]
{
    __shared__ unsigned short Qs[64][72];   // [qrow][d], +8 pad
    __shared__ unsigned short Ks[64][72];   // [krow][d]
    __shared__ unsigned short Vt[64][72];   // [d][krow]
    __shared__ unsigned short Ps[64][72];   // [qrow][krow], wave-private rows

    const int tid = threadIdx.x;
    const int wave = tid >> 6, lane = tid & 63;
    const int l15 = lane & 15, lq = lane >> 4;
    const int qblk = gridDim.x - 1 - blockIdx.x;   // heaviest blocks first
    const int q0 = qblk * 64;
    const int bh = blockIdx.y;
    const size_t base = (size_t)bh * 2048 * 64;    // same offset for qb/kb/vtb

    // stage Q once
    #pragma unroll
    for (int i = 0; i < 2; ++i) {
        int c = tid + 256 * i;
        int row = c >> 3, g = c & 7;
        *(uint4*)&Qs[row][g*8] = *(const uint4*)(qb + base + (size_t)(q0 + row)*64 + g*8);
    }
    __syncthreads();
    short8 qf[2];
    qf[0] = *(const short8*)&Qs[wave*16 + l15][lq*8];
    qf[1] = *(const short8*)&Qs[wave*16 + l15][32 + lq*8];

    f32x4 o[4] = {};
    float mrow[4], lrow[4];
    #pragma unroll
    for (int r = 0; r < 4; ++r) { mrow[r] = -1e30f; lrow[r] = 0.0f; }

    for (int j0 = 0; j0 <= q0; j0 += 64) {
        __syncthreads();   // all waves done reading previous Ks/Vt
        #pragma unroll
        for (int i = 0; i < 2; ++i) {
            int c = tid + 256 * i;
            int row = c >> 3, g = c & 7;
            *(uint4*)&Ks[row][g*8] = *(const uint4*)(kb  + base + (size_t)(j0 + row)*64 + g*8);
            *(uint4*)&Vt[row][g*8] = *(const uint4*)(vtb + base + (size_t)row*2048 + j0 + g*8);
        }
        __syncthreads();

        // S = Q K^T  (16 q-rows x 64 keys per wave)
        f32x4 s[4] = {};
        #pragma unroll
        for (int ks = 0; ks < 2; ++ks)
            #pragma unroll
            for (int ni = 0; ni < 4; ++ni) {
                short8 kf = *(const short8*)&Ks[ni*16 + l15][ks*32 + lq*8];
                s[ni] = __builtin_amdgcn_mfma_f32_16x16x32_bf16(qf[ks], kf, s[ni], 0, 0, 0);
            }

        // causal mask: only the diagonal tile is partial
        if (j0 == q0) {
            #pragma unroll
            for (int ni = 0; ni < 4; ++ni)
                #pragma unroll
                for (int r = 0; r < 4; ++r) {
                    int qr = wave*16 + lq*4 + r;   // local q row
                    int kc = ni*16 + l15;          // local key col
                    if (kc > qr) s[ni][r] = -1e30f;
                }
        }

        // online softmax (rows live across the 16 lanes of each quad-group)
        float al[4];
        #pragma unroll
        for (int r = 0; r < 4; ++r) {
            float mx = fmaxf(fmaxf(s[0][r], s[1][r]), fmaxf(s[2][r], s[3][r]));
            #pragma unroll
            for (int off = 1; off < 16; off <<= 1)
                mx = fmaxf(mx, __shfl_xor(mx, off));
            float mnew = fmaxf(mrow[r], mx);
            al[r] = __expf(mrow[r] - mnew);
            mrow[r] = mnew;
        }
        #pragma unroll
        for (int r = 0; r < 4; ++r) {
            float sum = 0.0f;
            #pragma unroll
            for (int ni = 0; ni < 4; ++ni) {
                float p = __expf(s[ni][r] - mrow[r]);
                s[ni][r] = p;
                sum += p;
            }
            #pragma unroll
            for (int off = 1; off < 16; off <<= 1)
                sum += __shfl_xor(sum, off);
            lrow[r] = lrow[r] * al[r] + sum;
            #pragma unroll
            for (int ni = 0; ni < 4; ++ni)
                o[ni][r] *= al[r];
        }

        // P: C-layout regs -> wave-private LDS rows (A-layout source)
        #pragma unroll
        for (int ni = 0; ni < 4; ++ni)
            #pragma unroll
            for (int r = 0; r < 4; ++r)
                Ps[wave*16 + lq*4 + r][ni*16 + l15] = f2bf(s[ni][r]);

        // O += P V  (no barrier: Ps rows are wave-private; in-wave DS order)
        #pragma unroll
        for (int ks = 0; ks < 2; ++ks) {
            short8 pf = *(const short8*)&Ps[wave*16 + l15][ks*32 + lq*8];
            #pragma unroll
            for (int ni = 0; ni < 4; ++ni) {
                short8 vf = *(const short8*)&Vt[ni*16 + l15][ks*32 + lq*8];
                o[ni] = __builtin_amdgcn_mfma_f32_16x16x32_bf16(pf, vf, o[ni], 0, 0, 0);
            }
        }
    }

    // epilogue: O/l -> ab [B*T][C] bf16
    const int b = bh >> 4, h = bh & 15;
    #pragma unroll
    for (int ni = 0; ni < 4; ++ni)
        #pragma unroll
        for (int r = 0; r < 4; ++r) {
            int m = b*2048 + q0 + wave*16 + lq*4 + r;
            int col = h*64 + ni*16 + l15;
            ab[(size_t)m * 1024 + col] = f2bf(o[ni][r] / lrow[r]);
        }
}

extern "C" void kernel_launch(void* const* d_in, const int* in_sizes, int n_in,
                              void* d_out, int out_size, void* d_ws, size_t ws_size,
                              hipStream_t stream) {
    const float* x      = (const float*)d_in[0];   // [B,T,C]
    const float* w_qkv  = (const float*)d_in[1];   // [C,3C]
    const float* b_qkv  = (const float*)d_in[2];   // [3C]
    const float* w_proj = (const float*)d_in[3];   // [C,C]
    const float* b_proj = (const float*)d_in[4];   // [C]
    float* out = (float*)d_out;                    // [B,T,C] fp32

    unsigned short* xb     = (unsigned short*)d_ws;          // 8192*1024
    unsigned short* wqkvT  = xb + 8388608;                   // 3072*1024
    unsigned short* wprojT = wqkvT + 3145728;                // 1024*1024
    unsigned short* qbuf   = wprojT + 1048576;               // [B,H,T,D]
    unsigned short* kbuf   = qbuf + 8388608;                 // [B,H,T,D]
    unsigned short* vtbuf  = kbuf + 8388608;                 // [B,H,D,T]
    unsigned short* abuf   = vtbuf + 8388608;                // [B*T][C]
    // total: 46,137,344 bf16 elems = 92 MiB

    convert_bf16<<<8192, 256, 0, stream>>>(x, xb, 8388608);
    transpose_convert<<<dim3(96, 32), 256, 0, stream>>>(w_qkv, wqkvT, 1024, 3072);
    transpose_convert<<<dim3(32, 32), 256, 0, stream>>>(w_proj, wprojT, 1024, 1024);

    gemm_qkv<<<dim3(24, 64), 256, 0, stream>>>(xb, wqkvT, b_qkv, qbuf, kbuf, vtbuf);
    attn_mfma<<<dim3(32, 64), 256, 0, stream>>>(qbuf, kbuf, vtbuf, abuf);
    gemm_proj<<<dim3(8, 64), 256, 0, stream>>>(abuf, wprojT, b_proj, out);
}

// Round 3
// 318.972 us; speedup vs baseline: 6.1343x; 1.3290x over previous
//
#include <hip/hip_runtime.h>

#define B_ 4
#define T_ 2048
#define C_ 1024
#define H_ 16
#define D_ 64

typedef __attribute__((ext_vector_type(8))) short short8;
typedef __attribute__((ext_vector_type(4))) float f32x4;

// float -> bf16 with round-to-nearest-even
__device__ inline unsigned short f2bf(float f) {
    union { float f; unsigned u; } v; v.f = f;
    unsigned r = v.u + 0x7fffu + ((v.u >> 16) & 1u);
    return (unsigned short)(r >> 16);
}

// async 16B global -> LDS (wave-uniform LDS base + lane*16)
__device__ inline void async_ld16(const void* g, void* lds) {
    __builtin_amdgcn_global_load_lds(
        (const __attribute__((address_space(1))) unsigned int*)g,
        (__attribute__((address_space(3))) unsigned int*)lds, 16, 0, 0);
}

// ---------------------------------------------------------------------------
// fp32 -> bf16 flat convert (n multiple of 4)
// ---------------------------------------------------------------------------
__global__ __launch_bounds__(256) void convert_bf16(
    const float* __restrict__ src, unsigned short* __restrict__ dst, int n)
{
    int i = (blockIdx.x * 256 + threadIdx.x) * 4;
    if (i >= n) return;
    float4 v = *(const float4*)(src + i);
    ushort4 o;
    o.x = f2bf(v.x); o.y = f2bf(v.y); o.z = f2bf(v.z); o.w = f2bf(v.w);
    *(ushort4*)(dst + i) = o;
}

// ---------------------------------------------------------------------------
// src[R][C] fp32 -> dst[C][R] bf16 (32x32 LDS tiles, coalesced both sides)
// ---------------------------------------------------------------------------
__global__ __launch_bounds__(256) void transpose_convert(
    const float* __restrict__ src, unsigned short* __restrict__ dst, int R, int C)
{
    __shared__ float tile[32][33];
    const int bx = blockIdx.x;   // over C/32
    const int by = blockIdx.y;   // over R/32
    const int tx = threadIdx.x & 31, ty = threadIdx.x >> 5;
    #pragma unroll
    for (int r = 0; r < 32; r += 8)
        tile[ty + r][tx] = src[(size_t)(by*32 + ty + r) * C + bx*32 + tx];
    __syncthreads();
    #pragma unroll
    for (int r = 0; r < 32; r += 8)
        dst[(size_t)(bx*32 + ty + r) * R + by*32 + tx] = f2bf(tile[tx][ty + r]);
}

// ---------------------------------------------------------------------------
// bf16 MFMA GEMM, m97 structure: 128x128 tile, BK=32, global_load_lds(16B),
// A[m][k] bf16, BT[n][k] bf16, 4 waves (2x2), each 64x64 via 4x4 MFMA frags.
// QKV epilogue: +bias, split q/k/v, q*0.125, q/k -> [B,H,T,D], v -> [B,H,D,T].
// ---------------------------------------------------------------------------
__global__ __launch_bounds__(256) void gemm_qkv(
    const unsigned short* __restrict__ A,   // [8192][1024] bf16
    const unsigned short* __restrict__ BT,  // [3072][1024] bf16
    const float* __restrict__ bias,         // [3072] fp32
    unsigned short* __restrict__ qb, unsigned short* __restrict__ kb,
    unsigned short* __restrict__ vtb)
{
    __shared__ unsigned short As[128 * 32];
    __shared__ unsigned short Bs[128 * 32];
    const int tid = threadIdx.x;
    const int wave = tid >> 6, lane = tid & 63;
    const int wm = wave >> 1, wn = wave & 1;
    const int l15 = lane & 15, lq = lane >> 4;
    const int m0 = blockIdx.y * 128, n0 = blockIdx.x * 128;
    const int srow = tid >> 2;      // staging row 0..63
    const int sg = tid & 3;         // 16B group within 64B row

    f32x4 acc[4][4] = {};

    for (int k0 = 0; k0 < 1024; k0 += 32) {
        async_ld16(A  + (size_t)(m0 + srow)      * 1024 + k0 + sg*8, (char*)As + wave*1024);
        async_ld16(A  + (size_t)(m0 + 64 + srow) * 1024 + k0 + sg*8, (char*)As + 4096 + wave*1024);
        async_ld16(BT + (size_t)(n0 + srow)      * 1024 + k0 + sg*8, (char*)Bs + wave*1024);
        async_ld16(BT + (size_t)(n0 + 64 + srow) * 1024 + k0 + sg*8, (char*)Bs + 4096 + wave*1024);
        __syncthreads();
        short8 af[4], bf[4];
        #pragma unroll
        for (int i = 0; i < 4; ++i) {
            af[i] = *(const short8*)&As[(wm*64 + i*16 + l15) * 32 + lq*8];
            bf[i] = *(const short8*)&Bs[(wn*64 + i*16 + l15) * 32 + lq*8];
        }
        #pragma unroll
        for (int mi = 0; mi < 4; ++mi)
            #pragma unroll
            for (int ni = 0; ni < 4; ++ni)
                acc[mi][ni] = __builtin_amdgcn_mfma_f32_16x16x32_bf16(
                    af[mi], bf[ni], acc[mi][ni], 0, 0, 0);
        __syncthreads();
    }

    const int sel = n0 >> 10;   // 0=q 1=k 2=v (128 | 1024 so constant per block)
    #pragma unroll
    for (int mi = 0; mi < 4; ++mi) {
        #pragma unroll
        for (int ni = 0; ni < 4; ++ni) {
            const int n = n0 + wn*64 + ni*16 + l15;
            const float bs = bias[n];
            const int h = (n >> 6) & 15, d = n & 63;
            #pragma unroll
            for (int r = 0; r < 4; ++r) {
                const int m = m0 + wm*64 + mi*16 + lq*4 + r;  // C-layout row
                const int b = m >> 11, t = m & 2047;
                const size_t bh = (size_t)(b*16 + h);
                float v = acc[mi][ni][r] + bs;
                if (sel == 0)      qb[(bh*2048 + t)*64 + d] = f2bf(v * 0.125f);
                else if (sel == 1) kb[(bh*2048 + t)*64 + d] = f2bf(v);
                else               vtb[(bh*64 + d)*2048 + t] = f2bf(v);
            }
        }
    }
}

// ---------------------------------------------------------------------------
// Output projection GEMM: ab[8192][1024] bf16 @ wprojT[1024][1024] bf16 + bias
// -> out fp32 [8192][1024]
// ---------------------------------------------------------------------------
__global__ __launch_bounds__(256) void gemm_proj(
    const unsigned short* __restrict__ A,   // [8192][1024] bf16
    const unsigned short* __restrict__ BT,  // [1024][1024] bf16
    const float* __restrict__ bias,         // [1024]
    float* __restrict__ out)
{
    __shared__ unsigned short As[128 * 32];
    __shared__ unsigned short Bs[128 * 32];
    const int tid = threadIdx.x;
    const int wave = tid >> 6, lane = tid & 63;
    const int wm = wave >> 1, wn = wave & 1;
    const int l15 = lane & 15, lq = lane >> 4;
    const int m0 = blockIdx.y * 128, n0 = blockIdx.x * 128;
    const int srow = tid >> 2, sg = tid & 3;

    f32x4 acc[4][4] = {};

    for (int k0 = 0; k0 < 1024; k0 += 32) {
        async_ld16(A  + (size_t)(m0 + srow)      * 1024 + k0 + sg*8, (char*)As + wave*1024);
        async_ld16(A  + (size_t)(m0 + 64 + srow) * 1024 + k0 + sg*8, (char*)As + 4096 + wave*1024);
        async_ld16(BT + (size_t)(n0 + srow)      * 1024 + k0 + sg*8, (char*)Bs + wave*1024);
        async_ld16(BT + (size_t)(n0 + 64 + srow) * 1024 + k0 + sg*8, (char*)Bs + 4096 + wave*1024);
        __syncthreads();
        short8 af[4], bf[4];
        #pragma unroll
        for (int i = 0; i < 4; ++i) {
            af[i] = *(const short8*)&As[(wm*64 + i*16 + l15) * 32 + lq*8];
            bf[i] = *(const short8*)&Bs[(wn*64 + i*16 + l15) * 32 + lq*8];
        }
        #pragma unroll
        for (int mi = 0; mi < 4; ++mi)
            #pragma unroll
            for (int ni = 0; ni < 4; ++ni)
                acc[mi][ni] = __builtin_amdgcn_mfma_f32_16x16x32_bf16(
                    af[mi], bf[ni], acc[mi][ni], 0, 0, 0);
        __syncthreads();
    }

    #pragma unroll
    for (int mi = 0; mi < 4; ++mi)
        #pragma unroll
        for (int ni = 0; ni < 4; ++ni) {
            const int n = n0 + wn*64 + ni*16 + l15;
            const float bs = bias[n];
            #pragma unroll
            for (int r = 0; r < 4; ++r) {
                const int m = m0 + wm*64 + mi*16 + lq*4 + r;
                out[(size_t)m * 1024 + n] = acc[mi][ni][r] + bs;
            }
        }
}

// ---------------------------------------------------------------------------
// MFMA flash attention v2, causal.
// Block = 256 thr / 4 waves; processes TWO 128-row q-tiles (qblk i and 15-i)
// for one (b,h) -> exactly 34 k-tiles per block (perfect causal balance).
// Each wave owns 32 q-rows (2 m-frags) -> 2x ILP vs v1.
// Row-sum l computed by MFMA against a persistent ones-row in Vt (no shfl-sum
// chain); l obeys the same alpha-rescale recurrence as O.
// Waves skip fully-masked k-tiles. q pre-scaled by D^-0.5 in gemm_qkv.
// LDS: Ks 9.2K + Vt(80 rows: 64 data + ones/zeros) 11.5K + Ps 18.4K = 39.1KB.
// ---------------------------------------------------------------------------
__global__ __launch_bounds__(256) void attn_mfma(
    const unsigned short* __restrict__ qb,   // [B,H,T,D]
    const unsigned short* __restrict__ kb,   // [B,H,T,D]
    const unsigned short* __restrict__ vtb,  // [B,H,D,T]
    unsigned short* __restrict__ ab)         // [B*T][C]
{
    __shared__ unsigned short Ks[64][72];
    __shared__ unsigned short Vt[80][72];   // rows 64..79: row64=1.0, rest 0
    __shared__ unsigned short Ps[128][72];  // Q staging + P tiles (wave-private rows)

    const int tid  = threadIdx.x;
    const int wave = tid >> 6, lane = tid & 63;
    const int l15  = lane & 15, lq = lane >> 4;
    const int bh   = blockIdx.y;
    const int b    = bh >> 4, h = bh & 15;
    const size_t base = (size_t)bh * 2048 * 64;

    // init ones/zero rows (persist: staging only rewrites Vt rows 0..63)
    for (int i = tid; i < 16 * 72; i += 256) {
        int r = i / 72, c = i - r * 72;
        Vt[64 + r][c] = (r == 0) ? (unsigned short)0x3F80 : (unsigned short)0;
    }

    #pragma unroll 1
    for (int half = 0; half < 2; ++half) {
        const int qblk = half ? (15 - blockIdx.x) : blockIdx.x;
        const int q0 = qblk * 128;

        __syncthreads();   // prev half's Ps reads (and ones-init) complete
        // stage Q tile (128 rows) into Ps
        #pragma unroll
        for (int i = 0; i < 4; ++i) {
            int c = tid + 256 * i;
            int row = c >> 3, g = c & 7;
            *(uint4*)&Ps[row][g*8] =
                *(const uint4*)(qb + base + (size_t)(q0 + row)*64 + g*8);
        }
        __syncthreads();
        short8 qf[2][2];
        #pragma unroll
        for (int mi = 0; mi < 2; ++mi)
            #pragma unroll
            for (int ks = 0; ks < 2; ++ks)
                qf[mi][ks] = *(const short8*)&Ps[wave*32 + mi*16 + l15][ks*32 + lq*8];

        f32x4 o[2][4] = {};
        f32x4 lac[2] = {};
        float mrow[2][4];
        #pragma unroll
        for (int mi = 0; mi < 2; ++mi)
            #pragma unroll
            for (int r = 0; r < 4; ++r) mrow[mi][r] = -1e30f;

        const int wq_lo = q0 + wave * 32;     // this wave's lowest q row
        const int wq_hi = wq_lo + 31;         // highest
        const int jmax  = q0 + 64;            // last k-tile for the block

        for (int j0 = 0; j0 <= jmax; j0 += 64) {
            __syncthreads();   // all waves done with prev Ks/Vt
            #pragma unroll
            for (int i = 0; i < 2; ++i) {
                int c = tid + 256 * i;
                int row = c >> 3, g = c & 7;
                *(uint4*)&Ks[row][g*8] = *(const uint4*)(kb  + base + (size_t)(j0 + row)*64 + g*8);
                *(uint4*)&Vt[row][g*8] = *(const uint4*)(vtb + base + (size_t)row*2048 + j0 + g*8);
            }
            __syncthreads();
            if (j0 > wq_hi) continue;   // fully masked for this wave

            // S = Q K^T  (32 q-rows x 64 keys per wave)
            f32x4 s[2][4] = {};
            #pragma unroll
            for (int ks = 0; ks < 2; ++ks)
                #pragma unroll
                for (int ni = 0; ni < 4; ++ni) {
                    short8 kf = *(const short8*)&Ks[ni*16 + l15][ks*32 + lq*8];
                    s[0][ni] = __builtin_amdgcn_mfma_f32_16x16x32_bf16(qf[0][ks], kf, s[0][ni], 0, 0, 0);
                    s[1][ni] = __builtin_amdgcn_mfma_f32_16x16x32_bf16(qf[1][ks], kf, s[1][ni], 0, 0, 0);
                }

            // causal mask — only tiles overlapping this wave's diagonal
            if (j0 + 63 > wq_lo) {
                #pragma unroll
                for (int mi = 0; mi < 2; ++mi)
                    #pragma unroll
                    for (int ni = 0; ni < 4; ++ni)
                        #pragma unroll
                        for (int r = 0; r < 4; ++r) {
                            int qr = wq_lo + mi*16 + lq*4 + r;
                            int kc = j0 + ni*16 + l15;
                            if (kc > qr) s[mi][ni][r] = -1e30f;
                        }
            }

            // online softmax: register max-reduce; P -> wave-private LDS rows
            #pragma unroll
            for (int mi = 0; mi < 2; ++mi) {
                float al[4];
                #pragma unroll
                for (int r = 0; r < 4; ++r) {
                    float mx = fmaxf(fmaxf(s[mi][0][r], s[mi][1][r]),
                                     fmaxf(s[mi][2][r], s[mi][3][r]));
                    #pragma unroll
                    for (int off = 1; off < 16; off <<= 1)
                        mx = fmaxf(mx, __shfl_xor(mx, off));
                    float mnew = fmaxf(mrow[mi][r], mx);
                    al[r] = __expf(mrow[mi][r] - mnew);
                    mrow[mi][r] = mnew;
                }
                #pragma unroll
                for (int r = 0; r < 4; ++r) {
                    #pragma unroll
                    for (int ni = 0; ni < 4; ++ni) {
                        float p = __expf(s[mi][ni][r] - mrow[mi][r]);
                        Ps[wave*32 + mi*16 + lq*4 + r][ni*16 + l15] = f2bf(p);
                        o[mi][ni][r] *= al[r];
                    }
                    lac[mi][r] *= al[r];
                }
            }

            // O += P V ; l via ones-column (in-wave DS ordering, no barrier)
            #pragma unroll
            for (int ks = 0; ks < 2; ++ks) {
                short8 pf0 = *(const short8*)&Ps[wave*32 +      l15][ks*32 + lq*8];
                short8 pf1 = *(const short8*)&Ps[wave*32 + 16 + l15][ks*32 + lq*8];
                #pragma unroll
                for (int ni = 0; ni < 4; ++ni) {
                    short8 vf = *(const short8*)&Vt[ni*16 + l15][ks*32 + lq*8];
                    o[0][ni] = __builtin_amdgcn_mfma_f32_16x16x32_bf16(pf0, vf, o[0][ni], 0, 0, 0);
                    o[1][ni] = __builtin_amdgcn_mfma_f32_16x16x32_bf16(pf1, vf, o[1][ni], 0, 0, 0);
                }
                short8 vl = *(const short8*)&Vt[64 + l15][ks*32 + lq*8];
                lac[0] = __builtin_amdgcn_mfma_f32_16x16x32_bf16(pf0, vl, lac[0], 0, 0, 0);
                lac[1] = __builtin_amdgcn_mfma_f32_16x16x32_bf16(pf1, vl, lac[1], 0, 0, 0);
            }
        }

        // epilogue: O/l -> ab [B*T][C] bf16 (l lives in lane lq*16 of each group)
        #pragma unroll
        for (int mi = 0; mi < 2; ++mi)
            #pragma unroll
            for (int r = 0; r < 4; ++r) {
                float l = __shfl(lac[mi][r], (lane & 48));
                float linv = 1.0f / l;
                int m = b*2048 + q0 + wave*32 + mi*16 + lq*4 + r;
                #pragma unroll
                for (int ni = 0; ni < 4; ++ni)
                    ab[(size_t)m * 1024 + h*64 + ni*16 + l15] = f2bf(o[mi][ni][r] * linv);
            }
    }
}

extern "C" void kernel_launch(void* const* d_in, const int* in_sizes, int n_in,
                              void* d_out, int out_size, void* d_ws, size_t ws_size,
                              hipStream_t stream) {
    const float* x      = (const float*)d_in[0];   // [B,T,C]
    const float* w_qkv  = (const float*)d_in[1];   // [C,3C]
    const float* b_qkv  = (const float*)d_in[2];   // [3C]
    const float* w_proj = (const float*)d_in[3];   // [C,C]
    const float* b_proj = (const float*)d_in[4];   // [C]
    float* out = (float*)d_out;                    // [B,T,C] fp32

    unsigned short* xb     = (unsigned short*)d_ws;          // 8192*1024
    unsigned short* wqkvT  = xb + 8388608;                   // 3072*1024
    unsigned short* wprojT = wqkvT + 3145728;                // 1024*1024
    unsigned short* qbuf   = wprojT + 1048576;               // [B,H,T,D]
    unsigned short* kbuf   = qbuf + 8388608;                 // [B,H,T,D]
    unsigned short* vtbuf  = kbuf + 8388608;                 // [B,H,D,T]
    unsigned short* abuf   = vtbuf + 8388608;                // [B*T][C]
    // total: 46,137,344 bf16 elems = 92 MiB

    convert_bf16<<<8192, 256, 0, stream>>>(x, xb, 8388608);
    transpose_convert<<<dim3(96, 32), 256, 0, stream>>>(w_qkv, wqkvT, 1024, 3072);
    transpose_convert<<<dim3(32, 32), 256, 0, stream>>>(w_proj, wprojT, 1024, 1024);

    gemm_qkv<<<dim3(24, 64), 256, 0, stream>>>(xb, wqkvT, b_qkv, qbuf, kbuf, vtbuf);
    attn_mfma<<<dim3(8, 64), 256, 0, stream>>>(qbuf, kbuf, vtbuf, abuf);
    gemm_proj<<<dim3(8, 64), 256, 0, stream>>>(abuf, wprojT, b_proj, out);
}

// Round 4
// 297.478 us; speedup vs baseline: 6.5775x; 1.0723x over previous
//
#include <hip/hip_runtime.h>

#define B_ 4
#define T_ 2048
#define C_ 1024
#define H_ 16
#define D_ 64

typedef __attribute__((ext_vector_type(8))) short short8;
typedef __attribute__((ext_vector_type(4))) float f32x4;

// float -> bf16 with round-to-nearest-even (fallback path)
__device__ inline unsigned short f2bf(float f) {
    union { float f; unsigned u; } v; v.f = f;
    unsigned r = v.u + 0x7fffu + ((v.u >> 16) & 1u);
    return (unsigned short)(r >> 16);
}

// pack two fp32 -> packed bf16x2 (hardware v_cvt_pk_bf16_f32 on gfx950)
__device__ inline unsigned int pk_bf16(float a, float b) {
#if __has_builtin(__builtin_amdgcn_cvt_pk_bf16_f32)
    typedef __attribute__((ext_vector_type(2))) __bf16 bf16x2;
    bf16x2 v = __builtin_amdgcn_cvt_pk_bf16_f32(a, b);
    return __builtin_bit_cast(unsigned int, v);
#else
    return (unsigned)f2bf(a) | ((unsigned)f2bf(b) << 16);
#endif
}

// 16-lane max reduce in pure VALU via DPP (quad_perm xor1, xor2,
// row_half_mirror, row_mirror) — no LDS/ds_swizzle latency.
__device__ inline float dpp_max16(float x) {
    int t;
    t = __builtin_amdgcn_update_dpp(0, __builtin_bit_cast(int, x), 0xB1, 0xF, 0xF, true);
    x = fmaxf(x, __builtin_bit_cast(float, t));
    t = __builtin_amdgcn_update_dpp(0, __builtin_bit_cast(int, x), 0x4E, 0xF, 0xF, true);
    x = fmaxf(x, __builtin_bit_cast(float, t));
    t = __builtin_amdgcn_update_dpp(0, __builtin_bit_cast(int, x), 0x141, 0xF, 0xF, true);
    x = fmaxf(x, __builtin_bit_cast(float, t));
    t = __builtin_amdgcn_update_dpp(0, __builtin_bit_cast(int, x), 0x140, 0xF, 0xF, true);
    x = fmaxf(x, __builtin_bit_cast(float, t));
    return x;
}

// async 16B global -> LDS (wave-uniform LDS base + lane*16)
__device__ inline void async_ld16(const void* g, void* lds) {
    __builtin_amdgcn_global_load_lds(
        (const __attribute__((address_space(1))) unsigned int*)g,
        (__attribute__((address_space(3))) unsigned int*)lds, 16, 0, 0);
}

// ---------------------------------------------------------------------------
// fp32 -> bf16 flat convert (n multiple of 4)
// ---------------------------------------------------------------------------
__global__ __launch_bounds__(256) void convert_bf16(
    const float* __restrict__ src, unsigned short* __restrict__ dst, int n)
{
    int i = (blockIdx.x * 256 + threadIdx.x) * 4;
    if (i >= n) return;
    float4 v = *(const float4*)(src + i);
    uint2 o;
    o.x = pk_bf16(v.x, v.y);
    o.y = pk_bf16(v.z, v.w);
    *(uint2*)(dst + i) = o;
}

// ---------------------------------------------------------------------------
// Merged weight prep: w_qkv[1024][3072] -> wqkvT[3072][1024] bf16 and
// w_proj[1024][1024] -> wprojT[1024][1024] bf16. 32x32 LDS tiles.
// grid (96+32, 32): bx<96 -> qkv, else proj.
// ---------------------------------------------------------------------------
__global__ __launch_bounds__(256) void prep_weights(
    const float* __restrict__ w_qkv, const float* __restrict__ w_proj,
    unsigned short* __restrict__ wqkvT, unsigned short* __restrict__ wprojT)
{
    __shared__ float tile[32][33];
    int bx = blockIdx.x;
    const int by = blockIdx.y;
    const float* src; unsigned short* dst; int Cc;
    if (bx < 96) { src = w_qkv; dst = wqkvT; Cc = 3072; }
    else         { src = w_proj; dst = wprojT; Cc = 1024; bx -= 96; }
    const int R = 1024;
    const int tx = threadIdx.x & 31, ty = threadIdx.x >> 5;
    #pragma unroll
    for (int r = 0; r < 32; r += 8)
        tile[ty + r][tx] = src[(size_t)(by*32 + ty + r) * Cc + bx*32 + tx];
    __syncthreads();
    #pragma unroll
    for (int r = 0; r < 32; r += 8)
        dst[(size_t)(bx*32 + ty + r) * R + by*32 + tx] = f2bf(tile[tx][ty + r]);
}

// ---------------------------------------------------------------------------
// QKV GEMM, m97 structure: 128x128 tile, BK=32, global_load_lds(16B).
// For q/k tiles the MFMA operand order is SWAPPED so each lane's 4 acc
// values are contiguous along d -> packed 8B stores to [B,H,T,D].
// For v tiles normal order -> 4 contiguous t -> packed 8B stores to [B,H,D,T].
// q scaled by D^-0.5 * log2(e) (exp2-domain softmax downstream).
// ---------------------------------------------------------------------------
__global__ __launch_bounds__(256) void gemm_qkv(
    const unsigned short* __restrict__ A,   // [8192][1024] bf16
    const unsigned short* __restrict__ BT,  // [3072][1024] bf16
    const float* __restrict__ bias,         // [3072] fp32
    unsigned short* __restrict__ qb, unsigned short* __restrict__ kb,
    unsigned short* __restrict__ vtb)
{
    __shared__ unsigned short As[128 * 32];
    __shared__ unsigned short Bs[128 * 32];
    const int tid = threadIdx.x;
    const int wave = tid >> 6, lane = tid & 63;
    const int wm = wave >> 1, wn = wave & 1;
    const int l15 = lane & 15, lq = lane >> 4;
    const int m0 = blockIdx.y * 128, n0 = blockIdx.x * 128;
    const int srow = tid >> 2, sg = tid & 3;
    const int sel = n0 >> 10;   // 0=q 1=k 2=v (block-uniform)

    f32x4 acc[4][4] = {};

    for (int k0 = 0; k0 < 1024; k0 += 32) {
        async_ld16(A  + (size_t)(m0 + srow)      * 1024 + k0 + sg*8, (char*)As + wave*1024);
        async_ld16(A  + (size_t)(m0 + 64 + srow) * 1024 + k0 + sg*8, (char*)As + 4096 + wave*1024);
        async_ld16(BT + (size_t)(n0 + srow)      * 1024 + k0 + sg*8, (char*)Bs + wave*1024);
        async_ld16(BT + (size_t)(n0 + 64 + srow) * 1024 + k0 + sg*8, (char*)Bs + 4096 + wave*1024);
        __syncthreads();
        short8 af[4], bf[4];
        #pragma unroll
        for (int i = 0; i < 4; ++i) {
            af[i] = *(const short8*)&As[(wm*64 + i*16 + l15) * 32 + lq*8];
            bf[i] = *(const short8*)&Bs[(wn*64 + i*16 + l15) * 32 + lq*8];
        }
        if (sel < 2) {
            #pragma unroll
            for (int mi = 0; mi < 4; ++mi)
                #pragma unroll
                for (int ni = 0; ni < 4; ++ni)
                    acc[mi][ni] = __builtin_amdgcn_mfma_f32_16x16x32_bf16(
                        bf[ni], af[mi], acc[mi][ni], 0, 0, 0);  // D[n][m]
        } else {
            #pragma unroll
            for (int mi = 0; mi < 4; ++mi)
                #pragma unroll
                for (int ni = 0; ni < 4; ++ni)
                    acc[mi][ni] = __builtin_amdgcn_mfma_f32_16x16x32_bf16(
                        af[mi], bf[ni], acc[mi][ni], 0, 0, 0);  // D[m][n]
        }
        __syncthreads();
    }

    if (sel < 2) {
        // lane l15 -> t; reg r -> n (d). 4 consecutive d per lane -> 8B store.
        const float qs = (sel == 0) ? 0.180336880f : 1.0f;  // 0.125*log2(e) | 1
        unsigned short* dst = (sel == 0) ? qb : kb;
        #pragma unroll
        for (int mi = 0; mi < 4; ++mi) {
            const int t = m0 + wm*64 + mi*16 + l15;
            const int bb = t >> 11, tt = t & 2047;
            #pragma unroll
            for (int ni = 0; ni < 4; ++ni) {
                const int nb = n0 + wn*64 + ni*16 + lq*4;
                const int hh = (nb >> 6) & 15, d0 = nb & 63;
                float4 bv = *(const float4*)(bias + nb);
                float v0 = (acc[mi][ni][0] + bv.x) * qs;
                float v1 = (acc[mi][ni][1] + bv.y) * qs;
                float v2 = (acc[mi][ni][2] + bv.z) * qs;
                float v3 = (acc[mi][ni][3] + bv.w) * qs;
                uint2 pk; pk.x = pk_bf16(v0, v1); pk.y = pk_bf16(v2, v3);
                *(uint2*)(dst + ((size_t)(bb*16 + hh)*2048 + tt)*64 + d0) = pk;
            }
        }
    } else {
        // lane l15 -> n (d); reg r -> t. 4 consecutive t per lane -> 8B store.
        #pragma unroll
        for (int mi = 0; mi < 4; ++mi) {
            const int t0 = m0 + wm*64 + mi*16 + lq*4;
            const int bb = t0 >> 11, tt = t0 & 2047;
            #pragma unroll
            for (int ni = 0; ni < 4; ++ni) {
                const int n = n0 + wn*64 + ni*16 + l15;
                const int hh = (n >> 6) & 15, d = n & 63;
                const float bs = bias[n];
                uint2 pk;
                pk.x = pk_bf16(acc[mi][ni][0] + bs, acc[mi][ni][1] + bs);
                pk.y = pk_bf16(acc[mi][ni][2] + bs, acc[mi][ni][3] + bs);
                *(uint2*)(vtb + ((size_t)(bb*16 + hh)*64 + d)*2048 + tt) = pk;
            }
        }
    }
}

// ---------------------------------------------------------------------------
// Output projection GEMM (swapped operands -> float4 coalesced stores):
// ab[8192][1024] bf16 @ wprojT[1024][1024] bf16 + bias -> out fp32
// ---------------------------------------------------------------------------
__global__ __launch_bounds__(256) void gemm_proj(
    const unsigned short* __restrict__ A,   // [8192][1024] bf16
    const unsigned short* __restrict__ BT,  // [1024][1024] bf16
    const float* __restrict__ bias,         // [1024]
    float* __restrict__ out)
{
    __shared__ unsigned short As[128 * 32];
    __shared__ unsigned short Bs[128 * 32];
    const int tid = threadIdx.x;
    const int wave = tid >> 6, lane = tid & 63;
    const int wm = wave >> 1, wn = wave & 1;
    const int l15 = lane & 15, lq = lane >> 4;
    const int m0 = blockIdx.y * 128, n0 = blockIdx.x * 128;
    const int srow = tid >> 2, sg = tid & 3;

    f32x4 acc[4][4] = {};

    for (int k0 = 0; k0 < 1024; k0 += 32) {
        async_ld16(A  + (size_t)(m0 + srow)      * 1024 + k0 + sg*8, (char*)As + wave*1024);
        async_ld16(A  + (size_t)(m0 + 64 + srow) * 1024 + k0 + sg*8, (char*)As + 4096 + wave*1024);
        async_ld16(BT + (size_t)(n0 + srow)      * 1024 + k0 + sg*8, (char*)Bs + wave*1024);
        async_ld16(BT + (size_t)(n0 + 64 + srow) * 1024 + k0 + sg*8, (char*)Bs + 4096 + wave*1024);
        __syncthreads();
        short8 af[4], bf[4];
        #pragma unroll
        for (int i = 0; i < 4; ++i) {
            af[i] = *(const short8*)&As[(wm*64 + i*16 + l15) * 32 + lq*8];
            bf[i] = *(const short8*)&Bs[(wn*64 + i*16 + l15) * 32 + lq*8];
        }
        #pragma unroll
        for (int mi = 0; mi < 4; ++mi)
            #pragma unroll
            for (int ni = 0; ni < 4; ++ni)
                acc[mi][ni] = __builtin_amdgcn_mfma_f32_16x16x32_bf16(
                    bf[ni], af[mi], acc[mi][ni], 0, 0, 0);  // D[n][m]
        __syncthreads();
    }

    // lane l15 -> m; reg r -> n. float4 store of 4 consecutive n.
    #pragma unroll
    for (int mi = 0; mi < 4; ++mi) {
        const int m = m0 + wm*64 + mi*16 + l15;
        #pragma unroll
        for (int ni = 0; ni < 4; ++ni) {
            const int nb = n0 + wn*64 + ni*16 + lq*4;
            float4 bv = *(const float4*)(bias + nb);
            float4 o;
            o.x = acc[mi][ni][0] + bv.x;
            o.y = acc[mi][ni][1] + bv.y;
            o.z = acc[mi][ni][2] + bv.z;
            o.w = acc[mi][ni][3] + bv.w;
            *(float4*)(out + (size_t)m * 1024 + nb) = o;
        }
    }
}

// ---------------------------------------------------------------------------
// MFMA flash attention v3, causal, exp2-domain (q pre-scaled by 0.125*log2e).
// Block = 4 waves; pair of 64-row q-tiles (i, 31-i) -> 33 staged k-tiles,
// perfectly balanced. Grid 16x64 = 1024 blocks -> 4 blocks/CU (16 waves).
// XCD swizzle: all 16 blocks of one (b,h) share blockIdx%8 class.
// DPP max-reduce (VALU-rate), l via ones-row MFMA, packed bf16 converts.
// LDS: Ks 9.2K + Vt 11.5K + Ps 9.2K = 30KB.
// ---------------------------------------------------------------------------
__global__ __launch_bounds__(256, 4) void attn_mfma(
    const unsigned short* __restrict__ qb,   // [B,H,T,D]
    const unsigned short* __restrict__ kb,   // [B,H,T,D]
    const unsigned short* __restrict__ vtb,  // [B,H,D,T]
    unsigned short* __restrict__ ab)         // [B*T][C]
{
    __shared__ unsigned short Ks[64][72];
    __shared__ unsigned short Vt[80][72];   // rows 64..79: row64=1.0, rest 0
    __shared__ unsigned short Ps[64][72];   // Q staging + P tiles (wave-private rows)

    const int tid  = threadIdx.x;
    const int wave = tid >> 6, lane = tid & 63;
    const int l15  = lane & 15, lq = lane >> 4;
    const int linear = blockIdx.y * 16 + blockIdx.x;
    const int xc = linear & 7, jj = linear >> 3;
    const int bh = xc * 8 + (jj >> 4);     // 16 blocks of one bh share xc
    const int pair = jj & 15;
    const int b = bh >> 4, h = bh & 15;
    const size_t base = (size_t)bh * 2048 * 64;

    // persistent ones/zero rows (staging only rewrites Vt rows 0..63)
    for (int i = tid; i < 16 * 72; i += 256) {
        int r = i / 72, cc = i - r * 72;
        Vt[64 + r][cc] = (r == 0) ? (unsigned short)0x3F80 : (unsigned short)0;
    }

    #pragma unroll 1
    for (int half = 0; half < 2; ++half) {
        const int qblk = half ? (31 - pair) : pair;
        const int q0 = qblk * 64;

        __syncthreads();   // prev half's Ps/Vt reads (and ones-init) complete
        #pragma unroll
        for (int i = 0; i < 2; ++i) {
            int slot = tid + 256 * i;
            int row = slot >> 3, g = slot & 7;
            *(uint4*)&Ps[row][g*8] = *(const uint4*)(qb + base + (size_t)(q0 + row)*64 + g*8);
        }
        __syncthreads();
        short8 qf[2];
        qf[0] = *(const short8*)&Ps[wave*16 + l15][lq*8];
        qf[1] = *(const short8*)&Ps[wave*16 + l15][32 + lq*8];

        f32x4 o[4] = {}, lac = {};
        float mrow[4] = {-1e30f, -1e30f, -1e30f, -1e30f};

        for (int j0 = 0; j0 <= q0; j0 += 64) {
            __syncthreads();   // all waves done with prev Ks/Vt
            #pragma unroll
            for (int i = 0; i < 2; ++i) {
                int slot = tid + 256 * i;
                int row = slot >> 3, g = slot & 7;
                *(uint4*)&Ks[row][g*8] = *(const uint4*)(kb  + base + (size_t)(j0 + row)*64 + g*8);
                *(uint4*)&Vt[row][g*8] = *(const uint4*)(vtb + base + (size_t)row*2048 + j0 + g*8);
            }
            __syncthreads();

            // S = Q K^T (16 q-rows x 64 keys per wave)
            f32x4 s[4] = {};
            #pragma unroll
            for (int ks = 0; ks < 2; ++ks)
                #pragma unroll
                for (int ni = 0; ni < 4; ++ni) {
                    short8 kf = *(const short8*)&Ks[ni*16 + l15][ks*32 + lq*8];
                    s[ni] = __builtin_amdgcn_mfma_f32_16x16x32_bf16(qf[ks], kf, s[ni], 0, 0, 0);
                }

            // causal mask — only the diagonal tile
            if (j0 == q0) {
                #pragma unroll
                for (int ni = 0; ni < 4; ++ni) {
                    int kc = ni*16 + l15;
                    #pragma unroll
                    for (int r = 0; r < 4; ++r) {
                        int qr = wave*16 + lq*4 + r;
                        if (kc > qr) s[ni][r] = -1e30f;
                    }
                }
            }

            // online softmax (exp2 domain), DPP max-reduce
            float al[4];
            #pragma unroll
            for (int r = 0; r < 4; ++r) {
                float mx = fmaxf(fmaxf(s[0][r], s[1][r]), fmaxf(s[2][r], s[3][r]));
                mx = dpp_max16(mx);
                float mnew = fmaxf(mrow[r], mx);
                al[r] = __builtin_amdgcn_exp2f(mrow[r] - mnew);
                mrow[r] = mnew;
            }
            #pragma unroll
            for (int r = 0; r < 4; ++r) {
                float p0 = __builtin_amdgcn_exp2f(s[0][r] - mrow[r]);
                float p1 = __builtin_amdgcn_exp2f(s[1][r] - mrow[r]);
                float p2 = __builtin_amdgcn_exp2f(s[2][r] - mrow[r]);
                float p3 = __builtin_amdgcn_exp2f(s[3][r] - mrow[r]);
                unsigned pa = pk_bf16(p0, p1), pb = pk_bf16(p2, p3);
                const int row = wave*16 + lq*4 + r;
                Ps[row][l15]      = (unsigned short)pa;
                Ps[row][16 + l15] = (unsigned short)(pa >> 16);
                Ps[row][32 + l15] = (unsigned short)pb;
                Ps[row][48 + l15] = (unsigned short)(pb >> 16);
                o[0][r] *= al[r]; o[1][r] *= al[r];
                o[2][r] *= al[r]; o[3][r] *= al[r];
                lac[r] *= al[r];
            }

            // O += P V ; l via ones-column (wave-private Ps rows, no barrier)
            #pragma unroll
            for (int ks = 0; ks < 2; ++ks) {
                short8 pf = *(const short8*)&Ps[wave*16 + l15][ks*32 + lq*8];
                #pragma unroll
                for (int ni = 0; ni < 4; ++ni) {
                    short8 vf = *(const short8*)&Vt[ni*16 + l15][ks*32 + lq*8];
                    o[ni] = __builtin_amdgcn_mfma_f32_16x16x32_bf16(pf, vf, o[ni], 0, 0, 0);
                }
                short8 vl = *(const short8*)&Vt[64 + l15][ks*32 + lq*8];
                lac = __builtin_amdgcn_mfma_f32_16x16x32_bf16(pf, vl, lac, 0, 0, 0);
            }
        }

        // epilogue: O/l -> ab (l lives in lanes with l15==0)
        #pragma unroll
        for (int r = 0; r < 4; ++r) {
            float l = __shfl(lac[r], (lane & 48));
            float linv = __builtin_amdgcn_rcpf(l);
            int m = b*2048 + q0 + wave*16 + lq*4 + r;
            unsigned pa = pk_bf16(o[0][r]*linv, o[1][r]*linv);
            unsigned pb = pk_bf16(o[2][r]*linv, o[3][r]*linv);
            unsigned short* p = ab + (size_t)m*1024 + h*64;
            p[l15]      = (unsigned short)pa;
            p[16 + l15] = (unsigned short)(pa >> 16);
            p[32 + l15] = (unsigned short)pb;
            p[48 + l15] = (unsigned short)(pb >> 16);
        }
    }
}

extern "C" void kernel_launch(void* const* d_in, const int* in_sizes, int n_in,
                              void* d_out, int out_size, void* d_ws, size_t ws_size,
                              hipStream_t stream) {
    const float* x      = (const float*)d_in[0];   // [B,T,C]
    const float* w_qkv  = (const float*)d_in[1];   // [C,3C]
    const float* b_qkv  = (const float*)d_in[2];   // [3C]
    const float* w_proj = (const float*)d_in[3];   // [C,C]
    const float* b_proj = (const float*)d_in[4];   // [C]
    float* out = (float*)d_out;                    // [B,T,C] fp32

    unsigned short* xb     = (unsigned short*)d_ws;          // 8192*1024
    unsigned short* wqkvT  = xb + 8388608;                   // 3072*1024
    unsigned short* wprojT = wqkvT + 3145728;                // 1024*1024
    unsigned short* qbuf   = wprojT + 1048576;               // [B,H,T,D]
    unsigned short* kbuf   = qbuf + 8388608;                 // [B,H,T,D]
    unsigned short* vtbuf  = kbuf + 8388608;                 // [B,H,D,T]
    unsigned short* abuf   = vtbuf + 8388608;                // [B*T][C]
    // total: 46,137,344 bf16 elems = 92 MiB

    convert_bf16<<<8192, 256, 0, stream>>>(x, xb, 8388608);
    prep_weights<<<dim3(128, 32), 256, 0, stream>>>(w_qkv, w_proj, wqkvT, wprojT);

    gemm_qkv<<<dim3(24, 64), 256, 0, stream>>>(xb, wqkvT, b_qkv, qbuf, kbuf, vtbuf);
    attn_mfma<<<dim3(16, 64), 256, 0, stream>>>(qbuf, kbuf, vtbuf, abuf);
    gemm_proj<<<dim3(8, 64), 256, 0, stream>>>(abuf, wprojT, b_proj, out);
}